// Round 2
// baseline (1772.654 us; speedup 1.0000x reference)
//
#include <hip/hip_runtime.h>
#include <math.h>

#define NSTEPS 50
#define NHID   64
#define NFEAT  11

// tanh(x) = 1 - 2/(e^{2x}+1); v_exp + v_rcp, ~3e-7 abs err (absorbed by fp32
// state quantization: delta_corr*DT << ulp(v) -> no trajectory divergence).
__device__ __forceinline__ float fast_tanh(float x) {
    float e = __expf(x + x);
    return 1.0f - 2.0f * __builtin_amdgcn_rcpf(e + 1.0f);
}

__global__ void transpose_w2(const float* __restrict__ W2, float* __restrict__ W2T) {
    int i = blockIdx.x * blockDim.x + threadIdx.x;
    if (i < NHID * NHID) {
        int k = i >> 6, j = i & 63;
        W2T[j * NHID + k] = W2[k * NHID + j];
    }
}

// Apply M to every literal index 0..63 (token-pasting needs literals, not B+i).
#define REP64(M) \
  M(0)  M(1)  M(2)  M(3)  M(4)  M(5)  M(6)  M(7)  \
  M(8)  M(9)  M(10) M(11) M(12) M(13) M(14) M(15) \
  M(16) M(17) M(18) M(19) M(20) M(21) M(22) M(23) \
  M(24) M(25) M(26) M(27) M(28) M(29) M(30) M(31) \
  M(32) M(33) M(34) M(35) M(36) M(37) M(38) M(39) \
  M(40) M(41) M(42) M(43) M(44) M(45) M(46) M(47) \
  M(48) M(49) M(50) M(51) M(52) M(53) M(54) M(55) \
  M(56) M(57) M(58) M(59) M(60) M(61) M(62) M(63)

#define HINIT(j)  float h##j = b1[j];
#define HTANH(j)  h##j = fast_tanh(h##j);
#define L1S(j)    h##j = fmaf(fkv, Wp[j], h##j);
#define L1ROW(K, FK) { const float fkv = (FK); const float* __restrict__ Wp = W1 + (K) * NHID; REP64(L1S) }
#define L2S(k) { const float hk = h##k;              \
                 a0 = fmaf(hk, w0p[k], a0);          \
                 a1 = fmaf(hk, w1p[k], a1);          \
                 a2 = fmaf(hk, w2p[k], a2);          \
                 a3 = fmaf(hk, w3p[k], a3); }

__global__ __launch_bounds__(256, 2)
void phys_mlp_kernel(const float* __restrict__ inputs,
                     const float* __restrict__ W1,
                     const float* __restrict__ b1,
                     const float* __restrict__ W2T,
                     const float* __restrict__ b2,
                     const float* __restrict__ W3,
                     const float* __restrict__ b3,
                     const float* __restrict__ grav,
                     const float* __restrict__ fric,
                     float* __restrict__ out,
                     int nb) {
    int b = blockIdx.x * blockDim.x + threadIdx.x;
    if (b >= nb) return;

    const float DTF = 1.0f / 30.0f;
    float pg = __fmul_rn(grav[0], 40.0f);
    float fr = fabsf(fric[0]);

    const float4* in4 = (const float4*)(inputs + (size_t)b * NSTEPS * 8);
    float4 s0 = in4[0], s1 = in4[1];
    float p1x = s0.x, p1y = s0.y, p2x = s0.z, p2y = s0.w;
    float v1x = s1.x, v1y = s1.y, v2x = s1.z, v2y = s1.w;

    float4* o4 = (float4*)(out + (size_t)b * NSTEPS * 8);

    #pragma unroll 1
    for (int t = 0; t < NSTEPS; ++t) {
        o4[0] = make_float4(p1x, p1y, p2x, p2y);
        o4[1] = make_float4(v1x, v1y, v2x, v2y);
        o4 += 2;
        if (t == NSTEPS - 1) break;                // 50th update discarded by scan

        // ---------------- features (np op order, no contraction; named scalars) --
        float f0, f1, f2, f3, f4, f5, f6, f7, f8, f9, f10;
        {
            float r = __fsqrt_rn(__fadd_rn(__fmul_rn(p1x, p1x), __fmul_rn(p1y, p1y)));
            f0 = r;
            f1 = atan2f(p1y, p1x);
            f2 = __fdiv_rn(__fadd_rn(__fmul_rn(p1x, v1x), __fmul_rn(p1y, v1y)),
                           __fadd_rn(r, 1e-6f));
            float vt = __fdiv_rn(__fsub_rn(__fmul_rn(p1x, v1y), __fmul_rn(p1y, v1x)),
                                 __fadd_rn(__fmul_rn(r, r), 1e-6f));
            f3 = vt;
            f4 = __fmul_rn(r, vt);
        }
        {
            float r = __fsqrt_rn(__fadd_rn(__fmul_rn(p2x, p2x), __fmul_rn(p2y, p2y)));
            f5 = r;
            f6 = atan2f(p2y, p2x);
            f7 = __fdiv_rn(__fadd_rn(__fmul_rn(p2x, v2x), __fmul_rn(p2y, v2y)),
                           __fadd_rn(r, 1e-6f));
            float vt = __fdiv_rn(__fsub_rn(__fmul_rn(p2x, v2y), __fmul_rn(p2y, v2x)),
                                 __fadd_rn(__fmul_rn(r, r), 1e-6f));
            f8 = vt;
            f9 = __fmul_rn(r, vt);
        }
        {
            float dx = __fsub_rn(p2x, p1x), dy = __fsub_rn(p2y, p1y);
            f10 = __fsqrt_rn(__fadd_rn(__fmul_rn(dx, dx), __fmul_rn(dy, dy)));
        }

        // ---------------- layer 1: 11 -> 64 on 64 NAMED registers (no alloca) ----
        REP64(HINIT)
        L1ROW(0, f0)  L1ROW(1, f1)  L1ROW(2, f2)  L1ROW(3, f3)
        L1ROW(4, f4)  L1ROW(5, f5)  L1ROW(6, f6)  L1ROW(7, f7)
        L1ROW(8, f8)  L1ROW(9, f9)  L1ROW(10, f10)
        REP64(HTANH)

        // ---------------- layer 2 (64->64) fused with layer 3 (64->2) ------------
        // j-loop rolled (I$), named h regs, 4 independent FMA chains, W2T rows
        // contiguous + wave-uniform -> s_load_dwordx16.
        float c0 = b3[0], c1 = b3[1];
        #pragma unroll 1
        for (int j = 0; j < NHID; j += 4) {
            const float* __restrict__ w0p = W2T + (j << 6);
            const float* __restrict__ w1p = w0p + NHID;
            const float* __restrict__ w2p = w1p + NHID;
            const float* __restrict__ w3p = w2p + NHID;
            float a0 = b2[j], a1 = b2[j + 1], a2 = b2[j + 2], a3 = b2[j + 3];
            REP64(L2S)
            float t0 = fast_tanh(a0), t1 = fast_tanh(a1);
            float t2 = fast_tanh(a2), t3 = fast_tanh(a3);
            c0 = fmaf(t0, W3[(j + 0) * 2], c0);  c1 = fmaf(t0, W3[(j + 0) * 2 + 1], c1);
            c0 = fmaf(t1, W3[(j + 1) * 2], c0);  c1 = fmaf(t1, W3[(j + 1) * 2 + 1], c1);
            c0 = fmaf(t2, W3[(j + 2) * 2], c0);  c1 = fmaf(t2, W3[(j + 2) * 2 + 1], c1);
            c0 = fmaf(t3, W3[(j + 3) * 2], c0);  c1 = fmaf(t3, W3[(j + 3) * 2 + 1], c1);
        }
        float corr0 = __fmul_rn(c0, 0.1f);
        float corr1 = __fmul_rn(c1, 0.1f);

        // ---------------- integrate (non-fused, np op order) ---------------------
        float ax1 = __fadd_rn(__fsub_rn(0.0f, __fmul_rn(fr, v1x)), corr0);
        float ay1 = __fadd_rn(__fsub_rn(pg,   __fmul_rn(fr, v1y)), corr1);
        float ax2 = __fadd_rn(__fsub_rn(0.0f, __fmul_rn(fr, v2x)), corr0);
        float ay2 = __fadd_rn(__fsub_rn(pg,   __fmul_rn(fr, v2y)), corr1);
        float nv1x = __fadd_rn(v1x, __fmul_rn(ax1, DTF));
        float nv1y = __fadd_rn(v1y, __fmul_rn(ay1, DTF));
        float nv2x = __fadd_rn(v2x, __fmul_rn(ax2, DTF));
        float nv2y = __fadd_rn(v2y, __fmul_rn(ay2, DTF));
        float np1x = __fadd_rn(p1x, __fmul_rn(nv1x, DTF));
        float np1y = __fadd_rn(p1y, __fmul_rn(nv1y, DTF));
        float np2x = __fadd_rn(p2x, __fmul_rn(nv2x, DTF));
        float np2y = __fadd_rn(p2y, __fmul_rn(nv2y, DTF));

        // ---------------- bounce ------------------------------------------------
        nv1x = (np1x < 20.0f || np1x > 780.0f) ? __fmul_rn(-0.8f, nv1x) : nv1x;
        np1x = fminf(fmaxf(np1x, 20.0f), 780.0f);
        nv1y = (np1y < 20.0f || np1y > 580.0f) ? __fmul_rn(-0.8f, nv1y) : nv1y;
        np1y = fminf(fmaxf(np1y, 20.0f), 580.0f);
        nv2x = (np2x < 20.0f || np2x > 780.0f) ? __fmul_rn(-0.8f, nv2x) : nv2x;
        np2x = fminf(fmaxf(np2x, 20.0f), 780.0f);
        nv2y = (np2y < 20.0f || np2y > 580.0f) ? __fmul_rn(-0.8f, nv2y) : nv2y;
        np2y = fminf(fmaxf(np2y, 20.0f), 580.0f);

        p1x = np1x; p1y = np1y; p2x = np2x; p2y = np2y;
        v1x = nv1x; v1y = nv1y; v2x = nv2x; v2y = nv2y;
    }
}

extern "C" void kernel_launch(void* const* d_in, const int* in_sizes, int n_in,
                              void* d_out, int out_size, void* d_ws, size_t ws_size,
                              hipStream_t stream) {
    const float* inputs = (const float*)d_in[0];
    const float* W1     = (const float*)d_in[1];
    const float* b1     = (const float*)d_in[2];
    const float* W2     = (const float*)d_in[3];
    const float* b2     = (const float*)d_in[4];
    const float* W3     = (const float*)d_in[5];
    const float* b3     = (const float*)d_in[6];
    const float* grav   = (const float*)d_in[7];
    const float* fric   = (const float*)d_in[8];
    float* out = (float*)d_out;
    float* W2T = (float*)d_ws;
    int nb = in_sizes[0] / (NSTEPS * 8);

    transpose_w2<<<16, 256, 0, stream>>>(W2, W2T);
    int blocks = (nb + 255) / 256;
    phys_mlp_kernel<<<blocks, 256, 0, stream>>>(inputs, W1, b1, W2T, b2, W3, b3,
                                                grav, fric, out, nb);
}